// Round 10
// baseline (176.304 us; speedup 1.0000x reference)
//
#include <hip/hip_runtime.h>
#include <hip/hip_bf16.h>

typedef __bf16 bf16_t;
typedef __bf16 bf16x8 __attribute__((ext_vector_type(8)));
typedef float  f32x4  __attribute__((ext_vector_type(4)));
typedef unsigned long u64;
typedef u64 u64x2 __attribute__((ext_vector_type(2)));

__device__ __forceinline__ bf16x8 pack8(f32x4 a, f32x4 b) {
    bf16x8 h = { (bf16_t)a.x, (bf16_t)a.y, (bf16_t)a.z, (bf16_t)a.w,
                 (bf16_t)b.x, (bf16_t)b.y, (bf16_t)b.z, (bf16_t)b.w };
    return h;
}

// ---- fp8 e4m3 (OCP) conversion ----
#if __has_builtin(__builtin_amdgcn_cvt_pk_fp8_f32)
__device__ __forceinline__ unsigned char cvt1_e4m3(float x) {
    return (unsigned char)(__builtin_amdgcn_cvt_pk_fp8_f32(x, x, 0, false) & 0xff);
}
#else
__device__ __forceinline__ unsigned char cvt1_e4m3(float x) {
    unsigned u = __float_as_uint(x);
    unsigned sign = (u >> 24) & 0x80u;
    float a = fabsf(x);
    if (a < 7.8125e-3f) { int q = (int)(a * 512.0f + 0.5f); return (unsigned char)(sign | q); }
    if (a >= 448.0f) return (unsigned char)(sign | 0x7E);
    unsigned au = u & 0x7FFFFFFFu;
    unsigned lsb = (au >> 20) & 1u;
    au += 0x7FFFFu + lsb;
    int exp = (int)(au >> 23) - 127;
    unsigned man = (au >> 20) & 7u;
    return (unsigned char)(sign | ((unsigned)(exp + 7) << 3) | man);
}
#endif

// Fragment-major ELEMENT offset within a 16-row tile (any K).
__device__ __forceinline__ int frag_off_k(int row16, int k) {
    return ((k >> 6) << 10) + (((k >> 3) & 3) << 8) + (row16 << 4)
         + (((k >> 5) & 1) << 3) + (k & 7);
}

// ---------------------------------------------------------------------------
// wconv: W (fp32 [256,K]) -> fragment-major bf16. Also zeroes rowsum/colsum.
// ---------------------------------------------------------------------------
__global__ __launch_bounds__(256) void wconv(
    const float* __restrict__ Wx, const float* __restrict__ Wy,
    bf16_t* __restrict__ Wxt, bf16_t* __restrict__ Wyt,
    float* __restrict__ sums)
{
    int id = blockIdx.x * 256 + threadIdx.x;
    if (blockIdx.x < 64) sums[id] = 0.0f;

    int row, k0, K;
    const float* W;
    bf16_t* Wt;
    if (id < 32768) { W = Wx; Wt = Wxt; K = 1024; row = id >> 7; k0 = (id & 127) << 3; }
    else { int c = id - 32768; W = Wy; Wt = Wyt; K = 768; row = c / 96; k0 = (c % 96) << 3; }

    f32x4 lo = *reinterpret_cast<const f32x4*>(&W[(size_t)row * K + k0]);
    f32x4 hi = *reinterpret_cast<const f32x4*>(&W[(size_t)row * K + k0 + 4]);
    size_t off = (size_t)(row >> 4) * 16 * K + frag_off_k(row & 15, k0);
    *reinterpret_cast<bf16x8*>(Wt + off) = pack8(lo, hi);
}

// ---------------------------------------------------------------------------
// proj_norm: P = A@W^T + bias -> L2 row-normalize -> fp8 frag-major.
// BARRIER-FREE K-loop (the session's proven pattern): block = 16 rows x 256
// cols, 256 thr / 4 waves, wave cg = 64-col strip. A-frags built from TWO
// direct f32x4 loads of fp32 X/Y (16 shared rows -> L1-hot, segments fully
// consumed) + in-reg pack8; B-frags direct contiguous from frag-major bf16 W
// (L2-hot). 2-slab register pipeline. LDS (4.4 KB) only for norm epilogue.
// Grid 1024: [0,512) X rows (K=1024), [512,1024) Y rows (K=768). 4 blocks/CU.
// ---------------------------------------------------------------------------
__global__ __launch_bounds__(256) void proj_norm(
    const float* __restrict__ X, const float* __restrict__ Y,
    const bf16_t* __restrict__ Wxt, const float* __restrict__ bxp,
    const bf16_t* __restrict__ Wyt, const float* __restrict__ byp,
    unsigned char* __restrict__ Xt, unsigned char* __restrict__ Yt)
{
    __shared__ unsigned char obuf[4096];   // 16x256 fp8 frag-major (one tile)
    __shared__ float ssqL[4][16];          // [colGroup][row16]

    const int tid  = threadIdx.x;
    const int lane = tid & 63;
    const int cg   = tid >> 6;     // 0..3: cols cg*64
    const int quad = lane >> 4;
    const int c16  = lane & 15;

    const bool isY = blockIdx.x >= 512;
    const float*  A    = isY ? Y   : X;
    const bf16_t* Wt   = isY ? Wyt : Wxt;
    const float*  bias = isY ? byp : bxp;
    unsigned char* dst = isY ? Yt  : Xt;
    const int K = isY ? 768 : 1024;
    const int S = K >> 6;          // 64-K slabs: 16 or 12 (even)
    const int rowBase = (blockIdx.x & 511) * 16;

    // A: lane (c16=row, quad=k-chunk); 32B per lane per slab, rows shared by
    // all 4 waves (L1 hits). B: contiguous per-wave from frag-major W.
    const float* pA = A + (size_t)(rowBase + c16) * K + quad * 8;
    const bf16_t* pB[4];
    #pragma unroll
    for (int nf = 0; nf < 4; ++nf)
        pB[nf] = Wt + (size_t)(cg * 4 + nf) * 16 * K + quad * 256 + c16 * 16;

    f32x4  a0[4], a1[4];
    bf16x8 b0[4][2], b1[4][2];
    f32x4  acc[4] = {};

    auto loadA = [&](f32x4* av, int s) {
        const float* q = pA + s * 64;
        av[0] = *reinterpret_cast<const f32x4*>(q);
        av[1] = *reinterpret_cast<const f32x4*>(q + 4);
        av[2] = *reinterpret_cast<const f32x4*>(q + 32);
        av[3] = *reinterpret_cast<const f32x4*>(q + 36);
    };
    auto loadB = [&](bf16x8 (*bv)[2], int s) {
        #pragma unroll
        for (int nf = 0; nf < 4; ++nf) {
            const bf16_t* p = pB[nf] + s * 1024;
            bv[nf][0] = *reinterpret_cast<const bf16x8*>(p);
            bv[nf][1] = *reinterpret_cast<const bf16x8*>(p + 8);
        }
    };
    auto step = [&](const f32x4* av, const bf16x8 (*bv)[2]) {
        bf16x8 aF0 = pack8(av[0], av[1]);
        #pragma unroll
        for (int nf = 0; nf < 4; ++nf)
            acc[nf] = __builtin_amdgcn_mfma_f32_16x16x32_bf16(aF0, bv[nf][0], acc[nf], 0, 0, 0);
        bf16x8 aF1 = pack8(av[2], av[3]);
        #pragma unroll
        for (int nf = 0; nf < 4; ++nf)
            acc[nf] = __builtin_amdgcn_mfma_f32_16x16x32_bf16(aF1, bv[nf][1], acc[nf], 0, 0, 0);
    };

    loadA(a0, 0);
    loadB(b0, 0);
    for (int s = 0; s < S; s += 2) {
        if (s + 1 < S) { loadA(a1, s + 1); loadB(b1, s + 1); }
        step(a0, b0);
        if (s + 2 < S) { loadA(a0, s + 2); loadB(b0, s + 2); }
        step(a1, b1);
    }

    // ---- epilogue: +bias, ssq, normalize, fp8 frag-major store ----
    #pragma unroll
    for (int nf = 0; nf < 4; ++nf) {
        float bb = bias[cg * 64 + nf * 16 + c16];
        #pragma unroll
        for (int r = 0; r < 4; ++r) acc[nf][r] += bb;
    }

    #pragma unroll
    for (int r = 0; r < 4; ++r) {
        float v = 0.f;
        #pragma unroll
        for (int nf = 0; nf < 4; ++nf) v += acc[nf][r] * acc[nf][r];
        v += __shfl_xor(v, 1, 64);
        v += __shfl_xor(v, 2, 64);
        v += __shfl_xor(v, 4, 64);
        v += __shfl_xor(v, 8, 64);
        if (c16 == 0) ssqL[cg][quad * 4 + r] = v;
    }
    __syncthreads();

    #pragma unroll
    for (int r = 0; r < 4; ++r) {
        int row16 = quad * 4 + r;
        float t = ssqL[0][row16] + ssqL[1][row16] + ssqL[2][row16] + ssqL[3][row16];
        float inv = 1.0f / fmaxf(sqrtf(t), 1e-8f);
        #pragma unroll
        for (int nf = 0; nf < 4; ++nf) {
            int k = cg * 64 + nf * 16 + c16;
            obuf[frag_off_k(row16, k)] = cvt1_e4m3(acc[nf][r] * inv);
        }
    }
    __syncthreads();

    // coalesced copy-out: 4 KB, 16 B/thread (tile contiguous in global)
    *reinterpret_cast<f32x4*>(dst + (size_t)rowBase * 256 + tid * 16) =
        *reinterpret_cast<const f32x4*>(&obuf[tid * 16]);
}

// ---------------------------------------------------------------------------
// sim_gemm: e = exp(Xn @ Yn^T); rowsum/colsum/diag. BM=BN=128, K=256.
// R5-proven version: fragment-direct contiguous loads (1KB/wave from
// frag-major fp8, L1/L2-resident), register-pipelined, no K-loop barriers,
// LDS only for the epilogue reduction. Measured 47.5 us — do not touch.
// ---------------------------------------------------------------------------
__global__ __launch_bounds__(256) void sim_gemm(
    const unsigned char* __restrict__ Xt, const unsigned char* __restrict__ Yt,
    float* __restrict__ rowsum, float* __restrict__ colsum,
    float* __restrict__ pos)
{
    __shared__ float red[256];

    const int tid  = threadIdx.x;
    const int lane = tid & 63;
    const int wave = tid >> 6;
    const int quad = lane >> 4;
    const int c16  = lane & 15;
    const int wy   = wave >> 1;
    const int wx   = wave & 1;
    const int rowBase = blockIdx.x * 128;
    const int colBase = blockIdx.y * 128;

    const u64x2* pa[4];
    const u64x2* pb[4];
    #pragma unroll
    for (int mf = 0; mf < 4; ++mf)
        pa[mf] = reinterpret_cast<const u64x2*>(
            Xt + (size_t)(rowBase + wy * 64 + mf * 16) * 256 + quad * 256 + c16 * 16);
    #pragma unroll
    for (int nf = 0; nf < 4; ++nf)
        pb[nf] = reinterpret_cast<const u64x2*>(
            Yt + (size_t)(colBase + wx * 64 + nf * 16) * 256 + quad * 256 + c16 * 16);

    f32x4 acc[4][4] = {};

    auto loadf = [&](u64x2* A, u64x2* B, int slab) {
        #pragma unroll
        for (int i = 0; i < 4; ++i) {
            A[i] = pa[i][slab * 64];
            B[i] = pb[i][slab * 64];
        }
    };
    auto mm = [&](const u64x2* A, const u64x2* B) {
        #pragma unroll
        for (int mf = 0; mf < 4; ++mf)
            #pragma unroll
            for (int nf = 0; nf < 4; ++nf)
                acc[mf][nf] = __builtin_amdgcn_mfma_f32_16x16x32_fp8_fp8(
                    (long)A[mf].x, (long)B[nf].x, acc[mf][nf], 0, 0, 0);
        #pragma unroll
        for (int mf = 0; mf < 4; ++mf)
            #pragma unroll
            for (int nf = 0; nf < 4; ++nf)
                acc[mf][nf] = __builtin_amdgcn_mfma_f32_16x16x32_fp8_fp8(
                    (long)A[mf].y, (long)B[nf].y, acc[mf][nf], 0, 0, 0);
    };

    u64x2 A0[4], B0[4], A1[4], B1[4];
    loadf(A0, B0, 0);
    loadf(A1, B1, 1);
    mm(A0, B0);
    loadf(A0, B0, 2);
    mm(A1, B1);
    loadf(A1, B1, 3);
    mm(A0, B0);
    mm(A1, B1);

    // ---- epilogue ----
    #pragma unroll
    for (int mf = 0; mf < 4; ++mf)
        #pragma unroll
        for (int nf = 0; nf < 4; ++nf)
            #pragma unroll
            for (int r = 0; r < 4; ++r)
                acc[mf][nf][r] = __expf(acc[mf][nf][r]);   // TAU = 1

    if (rowBase == colBase) {
        #pragma unroll
        for (int mf = 0; mf < 4; ++mf)
            #pragma unroll
            for (int nf = 0; nf < 4; ++nf)
                #pragma unroll
                for (int r = 0; r < 4; ++r) {
                    int lrow = wy * 64 + mf * 16 + quad * 4 + r;
                    int lcol = wx * 64 + nf * 16 + c16;
                    if (lrow == lcol) pos[rowBase + lrow] = acc[mf][nf][r];
                }
    }

    float rs[4][4];
    #pragma unroll
    for (int mf = 0; mf < 4; ++mf)
        #pragma unroll
        for (int r = 0; r < 4; ++r) {
            float v = acc[mf][0][r] + acc[mf][1][r] + acc[mf][2][r] + acc[mf][3][r];
            v += __shfl_xor(v, 1, 64);
            v += __shfl_xor(v, 2, 64);
            v += __shfl_xor(v, 4, 64);
            v += __shfl_xor(v, 8, 64);
            rs[mf][r] = v;
        }

    float cs[4];
    #pragma unroll
    for (int nf = 0; nf < 4; ++nf) {
        float v = 0.f;
        #pragma unroll
        for (int mf = 0; mf < 4; ++mf)
            #pragma unroll
            for (int r = 0; r < 4; ++r)
                v += acc[mf][nf][r];
        v += __shfl_xor(v, 16, 64);
        v += __shfl_xor(v, 32, 64);
        cs[nf] = v;
    }

    red[tid] = 0.f;
    __syncthreads();

    if (c16 == 0) {
        #pragma unroll
        for (int mf = 0; mf < 4; ++mf)
            #pragma unroll
            for (int r = 0; r < 4; ++r)
                atomicAdd(&red[wy * 64 + mf * 16 + quad * 4 + r], rs[mf][r]);
    }
    if (quad == 0) {
        #pragma unroll
        for (int nf = 0; nf < 4; ++nf)
            atomicAdd(&red[128 + wx * 64 + nf * 16 + c16], cs[nf]);
    }
    __syncthreads();

    if (tid < 128) atomicAdd(&rowsum[rowBase + tid], red[tid]);
    else           atomicAdd(&colsum[colBase + tid - 128], red[tid]);
}

// ---------------------------------------------------------------------------
__global__ __launch_bounds__(256) void finalize(
    const float* __restrict__ rowsum, const float* __restrict__ colsum,
    const float* __restrict__ pos, float* __restrict__ out)
{
    int i = blockIdx.x * 256 + threadIdx.x;
    float p = pos[i];
    out[i] = logf(colsum[i] - p) + logf(rowsum[i] - p) - 2.0f * logf(p);
}

// ---------------------------------------------------------------------------
extern "C" void kernel_launch(void* const* d_in, const int* in_sizes, int n_in,
                              void* d_out, int out_size, void* d_ws, size_t ws_size,
                              hipStream_t stream) {
    const float* X  = (const float*)d_in[0];
    const float* Y  = (const float*)d_in[1];
    const float* Wx = (const float*)d_in[2];
    const float* bx = (const float*)d_in[3];
    const float* Wy = (const float*)d_in[4];
    const float* by = (const float*)d_in[5];
    float* out = (float*)d_out;

    char* ws = (char*)d_ws;
    unsigned char* Xt  = (unsigned char*)(ws);               // 2 MB fp8 frag-major
    unsigned char* Yt  = (unsigned char*)(ws + (2u << 20));  // 2 MB
    bf16_t*        Wxt = (bf16_t*)(ws + (4u << 20));         // 512 KB bf16 frag-major
    bf16_t*        Wyt = (bf16_t*)(ws + (4u << 20) + (512u << 10));  // 384 KB
    float* rowsum = (float*)(ws + (5u << 20));
    float* colsum = rowsum + 8192;
    float* pos    = colsum + 8192;

    wconv<<<224, 256, 0, stream>>>(Wx, Wy, Wxt, Wyt, rowsum);
    proj_norm<<<1024, 256, 0, stream>>>(X, Y, Wxt, bx, Wyt, by, Xt, Yt);
    sim_gemm<<<dim3(64, 64), 256, 0, stream>>>(Xt, Yt, rowsum, colsum, pos);
    finalize<<<32, 256, 0, stream>>>(rowsum, colsum, pos, out);
}

// Round 11
// 162.483 us; speedup vs baseline: 1.0851x; 1.0851x over previous
//
#include <hip/hip_runtime.h>
#include <hip/hip_bf16.h>

typedef __bf16 bf16_t;
typedef __bf16 bf16x8 __attribute__((ext_vector_type(8)));
typedef float  f32x4  __attribute__((ext_vector_type(4)));
typedef unsigned long u64;
typedef u64 u64x2 __attribute__((ext_vector_type(2)));

__device__ __forceinline__ bf16x8 pack8(f32x4 a, f32x4 b) {
    bf16x8 h = { (bf16_t)a.x, (bf16_t)a.y, (bf16_t)a.z, (bf16_t)a.w,
                 (bf16_t)b.x, (bf16_t)b.y, (bf16_t)b.z, (bf16_t)b.w };
    return h;
}

// 16B async global->LDS DMA. LDS dest is wave-uniform base + lane*16.
__device__ __forceinline__ void gl_lds16(const void* g, void* l) {
    __builtin_amdgcn_global_load_lds(
        (const __attribute__((address_space(1))) unsigned int*)g,
        (__attribute__((address_space(3))) unsigned int*)l, 16, 0, 0);
}

// ---- fp8 e4m3 (OCP) conversion ----
#if __has_builtin(__builtin_amdgcn_cvt_pk_fp8_f32)
__device__ __forceinline__ unsigned char cvt1_e4m3(float x) {
    return (unsigned char)(__builtin_amdgcn_cvt_pk_fp8_f32(x, x, 0, false) & 0xff);
}
#else
__device__ __forceinline__ unsigned char cvt1_e4m3(float x) {
    unsigned u = __float_as_uint(x);
    unsigned sign = (u >> 24) & 0x80u;
    float a = fabsf(x);
    if (a < 7.8125e-3f) { int q = (int)(a * 512.0f + 0.5f); return (unsigned char)(sign | q); }
    if (a >= 448.0f) return (unsigned char)(sign | 0x7E);
    unsigned au = u & 0x7FFFFFFFu;
    unsigned lsb = (au >> 20) & 1u;
    au += 0x7FFFFu + lsb;
    int exp = (int)(au >> 23) - 127;
    unsigned man = (au >> 20) & 7u;
    return (unsigned char)(sign | ((unsigned)(exp + 7) << 3) | man);
}
#endif

// Fragment-major ELEMENT offset within a 16-row tile (any K).
__device__ __forceinline__ int frag_off_k(int row16, int k) {
    return ((k >> 6) << 10) + (((k >> 3) & 3) << 8) + (row16 << 4)
         + (((k >> 5) & 1) << 3) + (k & 7);
}

// ---------------------------------------------------------------------------
// wconv: W (fp32 [256,K]) -> fragment-major bf16. Also zeroes rowsum/colsum.
// ---------------------------------------------------------------------------
__global__ __launch_bounds__(256) void wconv(
    const float* __restrict__ Wx, const float* __restrict__ Wy,
    bf16_t* __restrict__ Wxt, bf16_t* __restrict__ Wyt,
    float* __restrict__ sums)
{
    int id = blockIdx.x * 256 + threadIdx.x;
    if (blockIdx.x < 64) sums[id] = 0.0f;

    int row, k0, K;
    const float* W;
    bf16_t* Wt;
    if (id < 32768) { W = Wx; Wt = Wxt; K = 1024; row = id >> 7; k0 = (id & 127) << 3; }
    else { int c = id - 32768; W = Wy; Wt = Wyt; K = 768; row = c / 96; k0 = (c % 96) << 3; }

    f32x4 lo = *reinterpret_cast<const f32x4*>(&W[(size_t)row * K + k0]);
    f32x4 hi = *reinterpret_cast<const f32x4*>(&W[(size_t)row * K + k0 + 4]);
    size_t off = (size_t)(row >> 4) * 16 * K + frag_off_k(row & 15, k0);
    *reinterpret_cast<bf16x8*>(Wt + off) = pack8(lo, hi);
}

// ---------------------------------------------------------------------------
// proj_norm: P = A@W^T + bias -> L2 row-normalize -> fp8 frag-major.
// R8's measured-best structure: 512 thr (8 waves), BM=64 rows x 256 cols.
// Wave tile 32x64: rg = wave>>2 (32 rows), cg = wave&3 (64 cols), B-dup 2x.
// A: fp32 via async global_load_lds (HBM stream -> DMA+barrier is the right
//    regime), double-buffered, chunk-XOR swizzled, 1 barrier/slab.
// B: direct contiguous loads from frag-major bf16 W (L2-hot).
// Grid 256: [0,128) X rows (K=1024), [128,256) Y rows (K=768).
// ---------------------------------------------------------------------------
__global__ __launch_bounds__(512, 2) void proj_norm(
    const float* __restrict__ X, const float* __restrict__ Y,
    const bf16_t* __restrict__ Wxt, const float* __restrict__ bxp,
    const bf16_t* __restrict__ Wyt, const float* __restrict__ byp,
    unsigned char* __restrict__ Xt, unsigned char* __restrict__ Yt)
{
    __shared__ float Abuf[2][64 * 64];       // 16 KB x2, chunk-XOR swizzled
    __shared__ unsigned char obuf[16384];    // 64x256 fp8 frag-major
    __shared__ float ssqL[4][64];            // [colGroup][row]

    const int tid  = threadIdx.x;
    const int lane = tid & 63;
    const int wave = tid >> 6;     // 0..7
    const int quad = lane >> 4;
    const int c16  = lane & 15;
    const int rg   = wave >> 2;    // 0..1: rows rg*32
    const int cg   = wave & 3;     // 0..3: cols cg*64

    const bool isY = blockIdx.x >= 128;
    const float*  A    = isY ? Y   : X;
    const bf16_t* Wt   = isY ? Wyt : Wxt;
    const float*  bias = isY ? byp : bxp;
    unsigned char* dst = isY ? Yt  : Xt;
    const int K = isY ? 768 : 1024;
    const int S = K >> 6;           // 64-K slabs
    const int rowBase = (blockIdx.x & 127) * 64;

    // DMA slab s into buffer b: 2 instrs/thread, wave moves 8 rows x 256B
    auto stage = [&](int s, int b) {
        #pragma unroll
        for (int t = 0; t < 2; ++t) {
            int r0  = (wave * 2 + t) * 4;            // wave-uniform base row
            int row = r0 + (lane >> 4);
            int gch = (lane & 15) ^ (row & 15);      // swizzled source chunk
            gl_lds16(&A[(size_t)(rowBase + row) * K + s * 64 + gch * 4],
                     &Abuf[b][r0 * 64]);
        }
    };

    // A fragment: row = rg*32 + mf*16 + c16 (row&15 == c16)
    auto aFrag = [&](int b, int mf, int s2) -> bf16x8 {
        int row = rg * 32 + mf * 16 + c16;
        int e   = s2 * 8 + quad * 2;                 // even 16B-chunk index
        const float* base = &Abuf[b][row * 64];
        f32x4 lo = *reinterpret_cast<const f32x4*>(base + ((e ^ c16) << 2));
        f32x4 hi = *reinterpret_cast<const f32x4*>(base + (((e + 1) ^ c16) << 2));
        return pack8(lo, hi);
    };

    const bf16_t* pB[4];
    #pragma unroll
    for (int nf = 0; nf < 4; ++nf)
        pB[nf] = Wt + (size_t)(cg * 4 + nf) * 16 * K + quad * 256 + c16 * 16;

    f32x4 acc[2][4] = {};
    stage(0, 0);

    for (int s = 0; s < S; ++s) {
        const int b = s & 1;
        __syncthreads();                   // drains buf b's DMA (issued 1 iter ago)
        if (s + 1 < S) stage(s + 1, b ^ 1);
        #pragma unroll
        for (int s2 = 0; s2 < 2; ++s2) {
            bf16x8 bF[4];
            #pragma unroll
            for (int nf = 0; nf < 4; ++nf)
                bF[nf] = *reinterpret_cast<const bf16x8*>(pB[nf] + s * 1024 + s2 * 8);
            #pragma unroll
            for (int mf = 0; mf < 2; ++mf) {
                bf16x8 aF = aFrag(b, mf, s2);
                #pragma unroll
                for (int nf = 0; nf < 4; ++nf)
                    acc[mf][nf] = __builtin_amdgcn_mfma_f32_16x16x32_bf16(
                        aF, bF[nf], acc[mf][nf], 0, 0, 0);
            }
        }
    }

    // ---- epilogue: +bias, ssq, normalize, fp8 frag-major store ----
    #pragma unroll
    for (int nf = 0; nf < 4; ++nf) {
        float bb = bias[cg * 64 + nf * 16 + c16];
        #pragma unroll
        for (int mf = 0; mf < 2; ++mf)
            #pragma unroll
            for (int r = 0; r < 4; ++r) acc[mf][nf][r] += bb;
    }

    #pragma unroll
    for (int mf = 0; mf < 2; ++mf)
        #pragma unroll
        for (int r = 0; r < 4; ++r) {
            float v = 0.f;
            #pragma unroll
            for (int nf = 0; nf < 4; ++nf) v += acc[mf][nf][r] * acc[mf][nf][r];
            v += __shfl_xor(v, 1, 64);
            v += __shfl_xor(v, 2, 64);
            v += __shfl_xor(v, 4, 64);
            v += __shfl_xor(v, 8, 64);
            if (c16 == 0) ssqL[cg][rg * 32 + mf * 16 + quad * 4 + r] = v;
        }
    __syncthreads();

    #pragma unroll
    for (int mf = 0; mf < 2; ++mf)
        #pragma unroll
        for (int r = 0; r < 4; ++r) {
            int lr = rg * 32 + mf * 16 + quad * 4 + r;
            float t = ssqL[0][lr] + ssqL[1][lr] + ssqL[2][lr] + ssqL[3][lr];
            float inv = 1.0f / fmaxf(sqrtf(t), 1e-8f);
            #pragma unroll
            for (int nf = 0; nf < 4; ++nf) {
                int k = cg * 64 + nf * 16 + c16;
                obuf[((lr >> 4) << 12) + frag_off_k(lr & 15, k)] =
                    cvt1_e4m3(acc[mf][nf][r] * inv);
            }
        }
    __syncthreads();

    // coalesced copy-out: 16 KB, 32 B/thread (tiles contiguous in global)
    const f32x4* src = reinterpret_cast<const f32x4*>(&obuf[tid * 32]);
    f32x4* g = reinterpret_cast<f32x4*>(dst + (size_t)rowBase * 256 + tid * 32);
    g[0] = src[0];
    g[1] = src[1];
}

// ---------------------------------------------------------------------------
// sim_gemm: e = exp(Xn @ Yn^T); rowsum/colsum/diag. BM=BN=128, K=256.
// R5-proven K-loop (47.5 us): fragment-direct contiguous loads, register
// pipeline, no barriers. New: 1D grid with XCD-aware swizzle (id&7 = XCD,
// each XCD covers an 8-col stripe x all 64 row-blocks -> full Xt (2 MB) +
// its Yt stripe (256 KB) fit in the 4 MB per-XCD L2). Bijective remap:
// correctness-independent.
// ---------------------------------------------------------------------------
__global__ __launch_bounds__(256) void sim_gemm(
    const unsigned char* __restrict__ Xt, const unsigned char* __restrict__ Yt,
    float* __restrict__ rowsum, float* __restrict__ colsum,
    float* __restrict__ pos)
{
    __shared__ float red[256];

    const int tid  = threadIdx.x;
    const int lane = tid & 63;
    const int wave = tid >> 6;
    const int quad = lane >> 4;
    const int c16  = lane & 15;
    const int wy   = wave >> 1;
    const int wx   = wave & 1;

    // XCD swizzle: id&7 = XCD; b2>>6 picks the col within the XCD's stripe.
    const int id = blockIdx.x;          // 0..4095
    const int b2 = id >> 3;             // 0..511
    const int colBlk = (id & 7) * 8 + (b2 >> 6);   // 0..63
    const int rowBlk = b2 & 63;                    // 0..63
    const int rowBase = rowBlk * 128;
    const int colBase = colBlk * 128;

    const u64x2* pa[4];
    const u64x2* pb[4];
    #pragma unroll
    for (int mf = 0; mf < 4; ++mf)
        pa[mf] = reinterpret_cast<const u64x2*>(
            Xt + (size_t)(rowBase + wy * 64 + mf * 16) * 256 + quad * 256 + c16 * 16);
    #pragma unroll
    for (int nf = 0; nf < 4; ++nf)
        pb[nf] = reinterpret_cast<const u64x2*>(
            Yt + (size_t)(colBase + wx * 64 + nf * 16) * 256 + quad * 256 + c16 * 16);

    f32x4 acc[4][4] = {};

    auto loadf = [&](u64x2* A, u64x2* B, int slab) {
        #pragma unroll
        for (int i = 0; i < 4; ++i) {
            A[i] = pa[i][slab * 64];
            B[i] = pb[i][slab * 64];
        }
    };
    auto mm = [&](const u64x2* A, const u64x2* B) {
        #pragma unroll
        for (int mf = 0; mf < 4; ++mf)
            #pragma unroll
            for (int nf = 0; nf < 4; ++nf)
                acc[mf][nf] = __builtin_amdgcn_mfma_f32_16x16x32_fp8_fp8(
                    (long)A[mf].x, (long)B[nf].x, acc[mf][nf], 0, 0, 0);
        #pragma unroll
        for (int mf = 0; mf < 4; ++mf)
            #pragma unroll
            for (int nf = 0; nf < 4; ++nf)
                acc[mf][nf] = __builtin_amdgcn_mfma_f32_16x16x32_fp8_fp8(
                    (long)A[mf].y, (long)B[nf].y, acc[mf][nf], 0, 0, 0);
    };

    u64x2 A0[4], B0[4], A1[4], B1[4];
    loadf(A0, B0, 0);
    loadf(A1, B1, 1);
    mm(A0, B0);
    loadf(A0, B0, 2);
    mm(A1, B1);
    loadf(A1, B1, 3);
    mm(A0, B0);
    mm(A1, B1);

    // ---- epilogue ----
    #pragma unroll
    for (int mf = 0; mf < 4; ++mf)
        #pragma unroll
        for (int nf = 0; nf < 4; ++nf)
            #pragma unroll
            for (int r = 0; r < 4; ++r)
                acc[mf][nf][r] = __expf(acc[mf][nf][r]);   // TAU = 1

    if (rowBase == colBase) {
        #pragma unroll
        for (int mf = 0; mf < 4; ++mf)
            #pragma unroll
            for (int nf = 0; nf < 4; ++nf)
                #pragma unroll
                for (int r = 0; r < 4; ++r) {
                    int lrow = wy * 64 + mf * 16 + quad * 4 + r;
                    int lcol = wx * 64 + nf * 16 + c16;
                    if (lrow == lcol) pos[rowBase + lrow] = acc[mf][nf][r];
                }
    }

    float rs[4][4];
    #pragma unroll
    for (int mf = 0; mf < 4; ++mf)
        #pragma unroll
        for (int r = 0; r < 4; ++r) {
            float v = acc[mf][0][r] + acc[mf][1][r] + acc[mf][2][r] + acc[mf][3][r];
            v += __shfl_xor(v, 1, 64);
            v += __shfl_xor(v, 2, 64);
            v += __shfl_xor(v, 4, 64);
            v += __shfl_xor(v, 8, 64);
            rs[mf][r] = v;
        }

    float cs[4];
    #pragma unroll
    for (int nf = 0; nf < 4; ++nf) {
        float v = 0.f;
        #pragma unroll
        for (int mf = 0; mf < 4; ++mf)
            #pragma unroll
            for (int r = 0; r < 4; ++r)
                v += acc[mf][nf][r];
        v += __shfl_xor(v, 16, 64);
        v += __shfl_xor(v, 32, 64);
        cs[nf] = v;
    }

    red[tid] = 0.f;
    __syncthreads();

    if (c16 == 0) {
        #pragma unroll
        for (int mf = 0; mf < 4; ++mf)
            #pragma unroll
            for (int r = 0; r < 4; ++r)
                atomicAdd(&red[wy * 64 + mf * 16 + quad * 4 + r], rs[mf][r]);
    }
    if (quad == 0) {
        #pragma unroll
        for (int nf = 0; nf < 4; ++nf)
            atomicAdd(&red[128 + wx * 64 + nf * 16 + c16], cs[nf]);
    }
    __syncthreads();

    if (tid < 128) atomicAdd(&rowsum[rowBase + tid], red[tid]);
    else           atomicAdd(&colsum[colBase + tid - 128], red[tid]);
}

// ---------------------------------------------------------------------------
__global__ __launch_bounds__(256) void finalize(
    const float* __restrict__ rowsum, const float* __restrict__ colsum,
    const float* __restrict__ pos, float* __restrict__ out)
{
    int i = blockIdx.x * 256 + threadIdx.x;
    float p = pos[i];
    out[i] = logf(colsum[i] - p) + logf(rowsum[i] - p) - 2.0f * logf(p);
}

// ---------------------------------------------------------------------------
extern "C" void kernel_launch(void* const* d_in, const int* in_sizes, int n_in,
                              void* d_out, int out_size, void* d_ws, size_t ws_size,
                              hipStream_t stream) {
    const float* X  = (const float*)d_in[0];
    const float* Y  = (const float*)d_in[1];
    const float* Wx = (const float*)d_in[2];
    const float* bx = (const float*)d_in[3];
    const float* Wy = (const float*)d_in[4];
    const float* by = (const float*)d_in[5];
    float* out = (float*)d_out;

    char* ws = (char*)d_ws;
    unsigned char* Xt  = (unsigned char*)(ws);               // 2 MB fp8 frag-major
    unsigned char* Yt  = (unsigned char*)(ws + (2u << 20));  // 2 MB
    bf16_t*        Wxt = (bf16_t*)(ws + (4u << 20));         // 512 KB bf16 frag-major
    bf16_t*        Wyt = (bf16_t*)(ws + (4u << 20) + (512u << 10));  // 384 KB
    float* rowsum = (float*)(ws + (5u << 20));
    float* colsum = rowsum + 8192;
    float* pos    = colsum + 8192;

    wconv<<<224, 256, 0, stream>>>(Wx, Wy, Wxt, Wyt, rowsum);
    proj_norm<<<256, 512, 0, stream>>>(X, Y, Wxt, bx, Wyt, by, Xt, Yt);
    sim_gemm<<<4096, 256, 0, stream>>>(Xt, Yt, rowsum, colsum, pos);
    finalize<<<32, 256, 0, stream>>>(rowsum, colsum, pos, out);
}